// Round 18
// baseline (37.047 us; speedup 1.0000x reference)
//
#include <hip/hip_runtime.h>
#include <math.h>

#define NB 8      // only channel 0 of C=32 survives the final slice
#define LL 512
#define DD 128
#define PP 96
#define QQ 3

// workspace layout (float offsets)
#define WS_BANDS 0
#define WS_CFR   16384                 // 229376 shorts = 114688 f32 (14 slices)
#define WS_WFR   (WS_CFR + 114688)     // 393216 shorts = 196608 f32

typedef __attribute__((ext_vector_type(8))) short short8v;
typedef __attribute__((ext_vector_type(4))) float f32x4;

#define MFMA16(a, b, c) __builtin_amdgcn_mfma_f32_16x16x32_bf16(a, b, c, 0, 0, 0)

__device__ __forceinline__ short f2bf(float f) {
  unsigned u = __builtin_bit_cast(unsigned, f);
  unsigned r = (u + 0x7fffu + ((u >> 16) & 1u)) >> 16;
  return (short)r;
}

// fast tanh via hardware exp: tanh(x) = sign(x) * (1-e)/(1+e), e = exp(-2|x|)
__device__ __forceinline__ float fast_tanh(float x) {
  float ax = fabsf(x);
  float e = __expf(-2.0f * ax);
  float r = (1.0f - e) / (1.0f + e);
  return x < 0.0f ? -r : r;
}

// tanh-form GELU (max dev from exact erf-GELU ~3e-3, fine for bf16 tolerance)
__device__ __forceinline__ float fast_gelu(float x) {
  float u = 0.7978845608028654f * x * (1.0f + 0.044715f * x * x);
  return 0.5f * x * (1.0f + fast_tanh(u));
}

constexpr float W_LO[8] = {
  -0.010597401784997278f, 0.032883011666982945f, 0.030841381835986965f,
  -0.18703481171888114f, -0.02798376941698385f, 0.6308807679295904f,
  0.7148465705525415f, 0.23037781330885523f
};

// ---------------- DWT helpers (validated round 0/1) ----------------
__device__ void dwt_level(const float* xin, int n, float* a, float* d,
                          int tid, int nthr) {
  int outn = (n + 5) / 2 + 1;
  for (int j = tid; j < outn; j += nthr) {
    float sa = 0.f, sd = 0.f;
#pragma unroll
    for (int k = 0; k < 8; ++k) {
      int i = 2 * j + k;
      int idx = (i < 6) ? (5 - i) : ((i < n + 6) ? (i - 6) : (2 * n + 5 - i));
      float v = xin[idx];
      sa += v * W_LO[7 - k];
      sd += v * ((k & 1) ? -W_LO[k] : W_LO[k]);
    }
    a[j] = sa;
    d[j] = sd;
  }
}

__device__ void idwt_level(const float* a, const float* d, float* out, int n,
                           int tid, int nthr) {
  int outn = 2 * n - 6;
  for (int t = tid; t < outn; t += nthr) {
    float s = 0.f;
#pragma unroll
    for (int k = 0; k < 8; ++k) {
      int j = t - 1 + k;
      if (j >= 0 && j <= 2 * n - 2 && ((j & 1) == 0)) {
        int m = j >> 1;
        if (a) s += a[m] * W_LO[k];
        if (d) s += d[m] * ((k & 1) ? W_LO[7 - k] : -W_LO[7 - k]);
      }
    }
    out[t] = s;
  }
}

// ---------------- K0: DWT (32) + packing (128) + out-bias init (1) ----------
struct PrepArgs {
  const float* x_enc;
  const float* cheb[4];
  const float* w1[4];
  const float* w2[4];
  const float* pred_b;
  const float* proj_w;
  const float* proj_b;
  float* bands;
  short* cfr;  // [slice14][ks4][nt8][lane64][e8]; band slice offsets {0,2,5,9}
  short* wfr;  // [(band*2+which)*3+tap][ks4][nt8][lane64][e8]
  float* out;  // initialized to pred_b[p]*S[q] + proj_b[q]
};

__global__ __launch_bounds__(256) void prep_kernel(PrepArgs a) {
  __shared__ float sx[LL];
  __shared__ float a1[259], d1[259], a2[133], d2[133], a3[70], d3[70];
  __shared__ float rA[LL], rB[LL];
  int bid = blockIdx.x, t = threadIdx.x;
  if (bid < 32) {
    int n = bid & 7, band = bid >> 3;
    for (int l = t; l < LL; l += 256)
      sx[l] = a.x_enc[(size_t)n * LL * 32 + (size_t)l * 32];  // channel 0
    __syncthreads();
    dwt_level(sx, 512, a1, d1, t, 256); __syncthreads();
    dwt_level(a1, 259, a2, d2, t, 256); __syncthreads();
    dwt_level(a2, 133, a3, d3, t, 256); __syncthreads();
    idwt_level(band == 0 ? a3 : nullptr, band == 1 ? d3 : nullptr, rA, 70, t, 256);
    __syncthreads();
    idwt_level(rA, band == 2 ? d2 : nullptr, rB, 133, t, 256);
    __syncthreads();
    idwt_level(rB, band == 3 ? d1 : nullptr, rA, 259, t, 256);
    __syncthreads();
    float* dstb = a.bands + ((size_t)band * NB + n) * LL;
    for (int l = t; l < LL; l += 256) dstb[l] = rA[l];
  } else if (bid < 160) {
    // fragment packing: 14 cheby slices (incl. k=0) + 24 conv slices
    const int CFRG = 28672, WFRG = 49152;
    const int total = CFRG + WFRG;
    for (int g = (bid - 32) * 256 + t; g < total; g += 128 * 256) {
      if (g < CFRG) {
        int gs = g >> 11, r = g & 2047;  // 2048 groups/slice
        int ks = r >> 9, r2 = r & 511;
        int nt = r2 >> 6, lane = r2 & 63;
        int b = (gs >= 9) ? 3 : ((gs >= 5) ? 2 : ((gs >= 2) ? 1 : 0));
        int off = (b == 3) ? 9 : ((b == 2) ? 5 : ((b == 1) ? 2 : 0));
        int kcoef = gs - off;  // 0..K-1 (0 = T0 slice)
        int K = b + 2;
        int din0 = ks * 32 + (lane >> 4) * 8;
        int dout = nt * 16 + (lane & 15);
        const float* src = a.cheb[b];
        short8v v;
#pragma unroll
        for (int el = 0; el < 8; ++el)
          v[el] = f2bf(src[((size_t)(din0 + el) * DD + dout) * K + kcoef]);
        ((short8v*)a.cfr)[g] = v;
      } else {
        int g2 = g - CFRG;
        int m = g2 >> 11, r = g2 & 2047;
        int ks = r >> 9, r2 = r & 511;
        int nt = r2 >> 6, lane = r2 & 63;
        int bw = m / 3, tap = m - bw * 3;
        int band = bw >> 1, which = bw & 1;
        const float* w = which ? a.w2[band] : a.w1[band];
        int din0 = ks * 32 + (lane >> 4) * 8;
        int dout = nt * 16 + (lane & 15);
        short8v v;
#pragma unroll
        for (int el = 0; el < 8; ++el)
          v[el] = f2bf(w[((size_t)dout * DD + din0 + el) * 3 + tap]);
        ((short8v*)a.wfr)[g2] = v;
      }
    }
  } else {
    // out[n][p][q] = pred_b[p]*S[q] + proj_b[q], S[q] = sum_d proj_w[q][d]
    __shared__ float S[4];
    if (t < QQ) {
      const float4* pw = (const float4*)(a.proj_w + (size_t)t * DD);
      float s = 0.f;
#pragma unroll
      for (int i = 0; i < 32; ++i) {
        float4 v = pw[i];
        s += v.x + v.y + v.z + v.w;
      }
      S[t] = s;
    }
    __syncthreads();
    for (int i = t; i < NB * PP * QQ; i += 256) {
      int pq = i % (PP * QQ);
      int p = pq / QQ, q = pq - p * QQ;
      a.out[i] = a.pred_b[p] * S[q] + a.proj_b[q];
    }
  }
}

// ---------------- main: role-split, 32-pos tiles, full-output epilogue -------
struct MainArgs {
  const float* emb_w;
  const float* bands;
  const short* cfr;
  const short* wfr;
  const float* proj_w;
  const float* pred_w;
  const float* b1[4];
  const float* b2[4];
  float* out;
};

// epilogue: tile[32][132] f32 in LDS -> proj dot (192 lanes, split-d) ->
// gq[32][3] -> pred contraction over the 32-l slice -> atomicAdd into out.
__device__ __forceinline__ void proj_epilogue(
    const MainArgs& ar, int n, int l0, float* tile, float* red, float* gq) {
  int t = threadIdx.x;
  __syncthreads();
  if (t < 192) {
    int pair = t % 96, half = t / 96;
    int p_loc = pair / 3, q = pair - (pair / 3) * 3;
    const float* pw = ar.proj_w + (size_t)q * DD + half * 64;
    const float* tr = tile + p_loc * 132 + half * 64;
    float sv = 0.f;
#pragma unroll 8
    for (int d = 0; d < 64; ++d) sv += tr[d] * pw[d];
    red[t] = sv;
  }
  __syncthreads();
  if (t < 96) gq[t] = red[t] + red[96 + t];
  __syncthreads();
  if (t < PP) {
    const float* pw = ar.pred_w + (size_t)t * LL + l0;
    float s0 = 0.f, s1 = 0.f, s2 = 0.f;
#pragma unroll 8
    for (int l = 0; l < 32; ++l) {
      float w = pw[l];
      s0 += w * gq[l * 3 + 0];
      s1 += w * gq[l * 3 + 1];
      s2 += w * gq[l * 3 + 2];
    }
    float* op = ar.out + (size_t)n * (PP * QQ) + t * 3;
    atomicAdd(op + 0, s0);
    atomicAdd(op + 1, s1);
    atomicAdd(op + 2, s2);
  }
}

// cheby role: NS = K slices; slice 0 = T0 (A = ones); band row read directly
// from global (broadcast loads) -- no blx LDS stage / barrier.
template <int NS>
__device__ __forceinline__ void cheby_core(
    const MainArgs& ar, int band, int n, int l0, short* sU,
    float* red, float* gq) {
  int t = threadIdx.x;
  const float* brow = ar.bands + ((size_t)band * NB + n) * LL;
  const float* ew = ar.emb_w;
  for (int idx = t; idx < 32 * DD; idx += 256) {
    int l = idx >> 7, dch = idx & 127;
    float bm = brow[(l0 + l - 1 + LL) & 511];
    float bc = brow[(l0 + l) & 511];
    float bp = brow[(l0 + l + 1) & 511];
    float e = ew[dch * 3] * bm + ew[dch * 3 + 1] * bc + ew[dch * 3 + 2] * bp;
    float x = fast_tanh(e);
    int o = l * 136 + dch;
    sU[o] = f2bf(x);
    if (NS >= 3) {
      float t2 = 2.f * x * x - 1.f;
      sU[4352 + o] = f2bf(t2);
      if (NS >= 4) {
        float t3 = 2.f * x * t2 - x;
        sU[8704 + o] = f2bf(t3);
        if (NS >= 5) sU[13056 + o] = f2bf(2.f * x * t3 - t2);
      }
    }
  }
  __syncthreads();

  int w = t >> 6, lane = t & 63;
  int r16 = lane & 15, kq = lane >> 4;
  const int sbase = (NS - 2) * (NS + 1) / 2;  // band slice offsets {0,2,5,9}
  const short8v* cfrv = (const short8v*)ar.cfr;
  const short ONEB = (short)0x3F80;  // bf16 1.0
  short8v ones = {ONEB, ONEB, ONEB, ONEB, ONEB, ONEB, ONEB, ONEB};
  f32x4 cacc[2][2];
#pragma unroll
  for (int i = 0; i < 2; ++i)
#pragma unroll
    for (int j = 0; j < 2; ++j) cacc[i][j] = (f32x4){0.f, 0.f, 0.f, 0.f};
#pragma unroll
  for (int s = 0; s < NS; ++s) {
    short8v bfr0[4], bfr1[4];
#pragma unroll
    for (int ks = 0; ks < 4; ++ks) {
      bfr0[ks] = cfrv[(((sbase + s) * 4 + ks) * 8 + w * 2 + 0) * 64 + lane];
      bfr1[ks] = cfrv[(((sbase + s) * 4 + ks) * 8 + w * 2 + 1) * 64 + lane];
    }
#pragma unroll
    for (int ks = 0; ks < 4; ++ks) {
      short8v a0, a1;
      if (s == 0) {
        a0 = ones;
        a1 = ones;
      } else {
        a0 = *(const short8v*)&sU[(s - 1) * 4352 + r16 * 136 + ks * 32 + kq * 8];
        a1 = *(const short8v*)&sU[(s - 1) * 4352 + (16 + r16) * 136 + ks * 32 + kq * 8];
      }
      cacc[0][0] = MFMA16(a0, bfr0[ks], cacc[0][0]);
      cacc[0][1] = MFMA16(a0, bfr1[ks], cacc[0][1]);
      cacc[1][0] = MFMA16(a1, bfr0[ks], cacc[1][0]);
      cacc[1][1] = MFMA16(a1, bfr1[ks], cacc[1][1]);
    }
  }
  __syncthreads();  // all MFMAs done reading planes before tile overlay
  float* tile = (float*)sU;  // [32][132] f32
  int row0 = kq * 4;
#pragma unroll
  for (int nt = 0; nt < 2; ++nt) {
    int dout = w * 32 + nt * 16 + r16;
#pragma unroll
    for (int m = 0; m < 2; ++m)
#pragma unroll
      for (int r = 0; r < 4; ++r)
        tile[(m * 16 + row0 + r) * 132 + dout] = cacc[m][nt][r];
  }
  proj_epilogue(ar, n, l0, tile, red, gq);
}

// conv role: band row read directly from global (broadcast loads); no blx2.
template <int DIL>
__device__ __forceinline__ void conv_core(
    const MainArgs& ar, int band, int n, int l0, short* sU,
    float* red, float* gq) {
  int t = threadIdx.x;
  const float* brow = ar.bands + ((size_t)band * NB + n) * LL;
  const float* ew = ar.emb_w;

  // emb extended tile: rows v in [0, 32+4*DIL), l = l0-2*DIL+v, zero outside
  const int ETR = 32 + 4 * DIL;  // 36/40/48/64
  for (int idx = t; idx < ETR * DD; idx += 256) {
    int v = idx >> 7, dch = idx & 127;
    int l = l0 - 2 * DIL + v;
    float e = 0.f;
    if (l >= 0 && l < LL) {
      float bm = brow[(l - 1 + LL) & 511];
      float bc = brow[l];
      float bp = brow[(l + 1) & 511];
      e = ew[dch * 3] * bm + ew[dch * 3 + 1] * bc + ew[dch * 3 + 2] * bp;
    }
    sU[v * 136 + dch] = f2bf(e);
  }
  __syncthreads();

  int w = t >> 6, lane = t & 63;
  int r16 = lane & 15, kq = lane >> 4;
  const short8v* wfrv = (const short8v*)ar.wfr;

  // conv1 over 48 extended rows (3 M-tiles)
  const int m3a = (band * 2) * 3;
  f32x4 acc1[3][2];
#pragma unroll
  for (int i = 0; i < 3; ++i)
#pragma unroll
    for (int j = 0; j < 2; ++j) acc1[i][j] = (f32x4){0.f, 0.f, 0.f, 0.f};
#pragma unroll
  for (int tap = 0; tap < 3; ++tap) {
    short8v bfr0[4], bfr1[4];
#pragma unroll
    for (int ks = 0; ks < 4; ++ks) {
      bfr0[ks] = wfrv[(((m3a + tap) * 4 + ks) * 8 + w * 2 + 0) * 64 + lane];
      bfr1[ks] = wfrv[(((m3a + tap) * 4 + ks) * 8 + w * 2 + 1) * 64 + lane];
    }
#pragma unroll
    for (int ks = 0; ks < 4; ++ks) {
#pragma unroll
      for (int m = 0; m < 3; ++m) {
        short8v av = *(const short8v*)&sU[(m * 16 + r16 + tap * DIL) * 136 + ks * 32 + kq * 8];
        acc1[m][0] = MFMA16(av, bfr0[ks], acc1[m][0]);
        acc1[m][1] = MFMA16(av, bfr1[ks], acc1[m][1]);
      }
    }
  }
  // y1_ext rows u (y1 at l = l0-DIL+u), zero outside valid range
  {
    float bias0 = ar.b1[band][w * 32 + r16];
    float bias1 = ar.b1[band][w * 32 + 16 + r16];
#pragma unroll
    for (int m = 0; m < 3; ++m)
#pragma unroll
      for (int r = 0; r < 4; ++r) {
        int u = m * 16 + kq * 4 + r;
        int l = l0 - DIL + u;
        bool valid = (l >= 0) && (l < LL) && (u < 32 + 2 * DIL);
        short v0 = valid ? f2bf(fast_gelu(acc1[m][0][r] + bias0)) : (short)0;
        short v1 = valid ? f2bf(fast_gelu(acc1[m][1][r] + bias1)) : (short)0;
        sU[8704 + u * 136 + w * 32 + r16] = v0;
        sU[8704 + u * 136 + w * 32 + 16 + r16] = v1;
      }
  }
  __syncthreads();

  // conv2 (A = y1_ext rows u = p + tap*DIL)
  const int m3b = (band * 2 + 1) * 3;
  f32x4 acc2[2][2];
#pragma unroll
  for (int i = 0; i < 2; ++i)
#pragma unroll
    for (int j = 0; j < 2; ++j) acc2[i][j] = (f32x4){0.f, 0.f, 0.f, 0.f};
#pragma unroll
  for (int tap = 0; tap < 3; ++tap) {
    short8v bfr0[4], bfr1[4];
#pragma unroll
    for (int ks = 0; ks < 4; ++ks) {
      bfr0[ks] = wfrv[(((m3b + tap) * 4 + ks) * 8 + w * 2 + 0) * 64 + lane];
      bfr1[ks] = wfrv[(((m3b + tap) * 4 + ks) * 8 + w * 2 + 1) * 64 + lane];
    }
#pragma unroll
    for (int ks = 0; ks < 4; ++ks) {
#pragma unroll
      for (int m = 0; m < 2; ++m) {
        short8v av = *(const short8v*)&sU[8704 + (m * 16 + r16 + tap * DIL) * 136 + ks * 32 + kq * 8];
        acc2[m][0] = MFMA16(av, bfr0[ks], acc2[m][0]);
        acc2[m][1] = MFMA16(av, bfr1[ks], acc2[m][1]);
      }
    }
  }

  // tile = gelu(conv2 + b2) + emb residual (f32 overlay, disjoint from y1_ext)
  float* tile = (float*)sU;
#pragma unroll
  for (int nt = 0; nt < 2; ++nt) {
    int dout = w * 32 + nt * 16 + r16;
    float b2v = ar.b2[band][dout];
    float w0 = ew[dout * 3], w1 = ew[dout * 3 + 1], w2 = ew[dout * 3 + 2];
#pragma unroll
    for (int m = 0; m < 2; ++m)
#pragma unroll
      for (int r = 0; r < 4; ++r) {
        int p = m * 16 + kq * 4 + r;
        float bm = brow[(l0 + p - 1 + LL) & 511];
        float bc = brow[(l0 + p) & 511];
        float bp = brow[(l0 + p + 1) & 511];
        float eres = w0 * bm + w1 * bc + w2 * bp;
        tile[p * 132 + dout] = fast_gelu(acc2[m][nt][r] + b2v) + eres;
      }
  }
  proj_epilogue(ar, n, l0, tile, red, gq);
}

__global__ __launch_bounds__(256) void main_kernel(MainArgs ar) {
  __shared__ __align__(16) short sU[17408];
  __shared__ float red[192];
  __shared__ float gq[96];
  int bid = blockIdx.x;
  int role = bid & 1, band = (bid >> 1) & 3, n = (bid >> 3) & 7;
  int l0 = (bid >> 6) << 5;
  if (role == 0) {
    switch (band) {
      case 0: cheby_core<2>(ar, band, n, l0, sU, red, gq); break;
      case 1: cheby_core<3>(ar, band, n, l0, sU, red, gq); break;
      case 2: cheby_core<4>(ar, band, n, l0, sU, red, gq); break;
      default: cheby_core<5>(ar, band, n, l0, sU, red, gq); break;
    }
  } else {
    switch (band) {
      case 0: conv_core<1>(ar, band, n, l0, sU, red, gq); break;
      case 1: conv_core<2>(ar, band, n, l0, sU, red, gq); break;
      case 2: conv_core<4>(ar, band, n, l0, sU, red, gq); break;
      default: conv_core<8>(ar, band, n, l0, sU, red, gq); break;
    }
  }
}

extern "C" void kernel_launch(void* const* d_in, const int* in_sizes, int n_in,
                              void* d_out, int out_size, void* d_ws, size_t ws_size,
                              hipStream_t stream) {
  const float* emb_w = (const float*)d_in[1];
  const float* proj_w = (const float*)d_in[22];
  const float* proj_b = (const float*)d_in[23];
  const float* pred_w = (const float*)d_in[24];
  const float* pred_b = (const float*)d_in[25];
  float* ws = (float*)d_ws;
  float* bands = ws + WS_BANDS;
  short* cfr = (short*)(ws + WS_CFR);
  short* wfr = (short*)(ws + WS_WFR);
  float* out = (float*)d_out;

  PrepArgs pa;
  pa.x_enc = (const float*)d_in[0];
  for (int i = 0; i < 4; ++i) {
    pa.cheb[i] = (const float*)d_in[2 + 5 * i];
    pa.w1[i] = (const float*)d_in[3 + 5 * i];
    pa.w2[i] = (const float*)d_in[5 + 5 * i];
  }
  pa.pred_b = pred_b; pa.proj_w = proj_w; pa.proj_b = proj_b;
  pa.bands = bands; pa.cfr = cfr; pa.wfr = wfr; pa.out = out;

  MainArgs ma;
  ma.emb_w = emb_w; ma.bands = bands; ma.cfr = cfr; ma.wfr = wfr;
  ma.proj_w = proj_w; ma.pred_w = pred_w;
  for (int i = 0; i < 4; ++i) {
    ma.b1[i] = (const float*)d_in[4 + 5 * i];
    ma.b2[i] = (const float*)d_in[6 + 5 * i];
  }
  ma.out = out;

  prep_kernel<<<161, 256, 0, stream>>>(pa);
  main_kernel<<<1024, 256, 0, stream>>>(ma);
}

// Round 19
// 33.203 us; speedup vs baseline: 1.1157x; 1.1157x over previous
//
#include <hip/hip_runtime.h>
#include <math.h>

#define NB 8      // only channel 0 of C=32 survives the final slice
#define LL 512
#define DD 128
#define PP 96
#define QQ 3

// workspace layout (float offsets)
#define WS_BANDS 0
#define WS_CFR   16384                 // 229376 shorts = 114688 f32 (14 slices)
#define WS_WFR   (WS_CFR + 114688)     // 393216 shorts = 196608 f32

typedef __attribute__((ext_vector_type(8))) short short8v;
typedef __attribute__((ext_vector_type(4))) float f32x4;

#define MFMA16(a, b, c) __builtin_amdgcn_mfma_f32_16x16x32_bf16(a, b, c, 0, 0, 0)

__device__ __forceinline__ short f2bf(float f) {
  unsigned u = __builtin_bit_cast(unsigned, f);
  unsigned r = (u + 0x7fffu + ((u >> 16) & 1u)) >> 16;
  return (short)r;
}

// fast tanh via hardware exp + rcp: tanh(x) = sign(x)*(1-e)*rcp(1+e), e=exp(-2|x|)
__device__ __forceinline__ float fast_tanh(float x) {
  float ax = fabsf(x);
  float e = __expf(-2.0f * ax);
  float r = (1.0f - e) * __builtin_amdgcn_rcpf(1.0f + e);
  return x < 0.0f ? -r : r;
}

// tanh-form GELU (max dev from exact erf-GELU ~3e-3, fine for bf16 tolerance)
__device__ __forceinline__ float fast_gelu(float x) {
  float u = 0.7978845608028654f * x * (1.0f + 0.044715f * x * x);
  return 0.5f * x * (1.0f + fast_tanh(u));
}

constexpr float W_LO[8] = {
  -0.010597401784997278f, 0.032883011666982945f, 0.030841381835986965f,
  -0.18703481171888114f, -0.02798376941698385f, 0.6308807679295904f,
  0.7148465705525415f, 0.23037781330885523f
};

// ---------------- DWT helpers (validated round 0/1) ----------------
__device__ void dwt_level(const float* xin, int n, float* a, float* d,
                          int tid, int nthr) {
  int outn = (n + 5) / 2 + 1;
  for (int j = tid; j < outn; j += nthr) {
    float sa = 0.f, sd = 0.f;
#pragma unroll
    for (int k = 0; k < 8; ++k) {
      int i = 2 * j + k;
      int idx = (i < 6) ? (5 - i) : ((i < n + 6) ? (i - 6) : (2 * n + 5 - i));
      float v = xin[idx];
      sa += v * W_LO[7 - k];
      sd += v * ((k & 1) ? -W_LO[k] : W_LO[k]);
    }
    a[j] = sa;
    d[j] = sd;
  }
}

__device__ void idwt_level(const float* a, const float* d, float* out, int n,
                           int tid, int nthr) {
  int outn = 2 * n - 6;
  for (int t = tid; t < outn; t += nthr) {
    float s = 0.f;
#pragma unroll
    for (int k = 0; k < 8; ++k) {
      int j = t - 1 + k;
      if (j >= 0 && j <= 2 * n - 2 && ((j & 1) == 0)) {
        int m = j >> 1;
        if (a) s += a[m] * W_LO[k];
        if (d) s += d[m] * ((k & 1) ? W_LO[7 - k] : -W_LO[7 - k]);
      }
    }
    out[t] = s;
  }
}

// ---------------- K0: DWT (32) + packing (128) + out-bias init (1) ----------
struct PrepArgs {
  const float* x_enc;
  const float* cheb[4];
  const float* w1[4];
  const float* w2[4];
  const float* pred_b;
  const float* proj_w;
  const float* proj_b;
  float* bands;
  short* cfr;  // [slice14][ks4][nt8][lane64][e8]; band slice offsets {0,2,5,9}
  short* wfr;  // [(band*2+which)*3+tap][ks4][nt8][lane64][e8]
  float* out;  // initialized to pred_b[p]*S[q] + proj_b[q]
};

__global__ __launch_bounds__(256) void prep_kernel(PrepArgs a) {
  __shared__ float sx[LL];
  __shared__ float a1[259], d1[259], a2[133], d2[133], a3[70], d3[70];
  __shared__ float rA[LL], rB[LL];
  int bid = blockIdx.x, t = threadIdx.x;
  if (bid < 32) {
    int n = bid & 7, band = bid >> 3;
    for (int l = t; l < LL; l += 256)
      sx[l] = a.x_enc[(size_t)n * LL * 32 + (size_t)l * 32];  // channel 0
    __syncthreads();
    dwt_level(sx, 512, a1, d1, t, 256); __syncthreads();
    dwt_level(a1, 259, a2, d2, t, 256); __syncthreads();
    dwt_level(a2, 133, a3, d3, t, 256); __syncthreads();
    idwt_level(band == 0 ? a3 : nullptr, band == 1 ? d3 : nullptr, rA, 70, t, 256);
    __syncthreads();
    idwt_level(rA, band == 2 ? d2 : nullptr, rB, 133, t, 256);
    __syncthreads();
    idwt_level(rB, band == 3 ? d1 : nullptr, rA, 259, t, 256);
    __syncthreads();
    float* dstb = a.bands + ((size_t)band * NB + n) * LL;
    for (int l = t; l < LL; l += 256) dstb[l] = rA[l];
  } else if (bid < 160) {
    // fragment packing: 14 cheby slices (incl. k=0) + 24 conv slices
    const int CFRG = 28672, WFRG = 49152;
    const int total = CFRG + WFRG;
    for (int g = (bid - 32) * 256 + t; g < total; g += 128 * 256) {
      if (g < CFRG) {
        int gs = g >> 11, r = g & 2047;  // 2048 groups/slice
        int ks = r >> 9, r2 = r & 511;
        int nt = r2 >> 6, lane = r2 & 63;
        int b = (gs >= 9) ? 3 : ((gs >= 5) ? 2 : ((gs >= 2) ? 1 : 0));
        int off = (b == 3) ? 9 : ((b == 2) ? 5 : ((b == 1) ? 2 : 0));
        int kcoef = gs - off;  // 0..K-1 (0 = T0 slice)
        int K = b + 2;
        int din0 = ks * 32 + (lane >> 4) * 8;
        int dout = nt * 16 + (lane & 15);
        const float* src = a.cheb[b];
        short8v v;
#pragma unroll
        for (int el = 0; el < 8; ++el)
          v[el] = f2bf(src[((size_t)(din0 + el) * DD + dout) * K + kcoef]);
        ((short8v*)a.cfr)[g] = v;
      } else {
        int g2 = g - CFRG;
        int m = g2 >> 11, r = g2 & 2047;
        int ks = r >> 9, r2 = r & 511;
        int nt = r2 >> 6, lane = r2 & 63;
        int bw = m / 3, tap = m - bw * 3;
        int band = bw >> 1, which = bw & 1;
        const float* w = which ? a.w2[band] : a.w1[band];
        int din0 = ks * 32 + (lane >> 4) * 8;
        int dout = nt * 16 + (lane & 15);
        short8v v;
#pragma unroll
        for (int el = 0; el < 8; ++el)
          v[el] = f2bf(w[((size_t)dout * DD + din0 + el) * 3 + tap]);
        ((short8v*)a.wfr)[g2] = v;
      }
    }
  } else {
    // out[n][p][q] = pred_b[p]*S[q] + proj_b[q], S[q] = sum_d proj_w[q][d]
    __shared__ float S[4];
    if (t < QQ) {
      const float4* pw = (const float4*)(a.proj_w + (size_t)t * DD);
      float s = 0.f;
#pragma unroll
      for (int i = 0; i < 32; ++i) {
        float4 v = pw[i];
        s += v.x + v.y + v.z + v.w;
      }
      S[t] = s;
    }
    __syncthreads();
    for (int i = t; i < NB * PP * QQ; i += 256) {
      int pq = i % (PP * QQ);
      int p = pq / QQ, q = pq - p * QQ;
      a.out[i] = a.pred_b[p] * S[q] + a.proj_b[q];
    }
  }
}

// ---------------- main: role-split, 32-pos tiles, full-output epilogue -------
struct MainArgs {
  const float* emb_w;
  const float* bands;
  const short* cfr;
  const short* wfr;
  const float* proj_w;
  const float* pred_w;
  const float* b1[4];
  const float* b2[4];
  float* out;
};

// epilogue: tile[32][132] f32 in LDS -> proj dot (192 lanes, split-d) ->
// gq[32][3] -> pred contraction over the 32-l slice -> atomicAdd into out.
__device__ __forceinline__ void proj_epilogue(
    const MainArgs& ar, int n, int l0, float* tile, float* red, float* gq) {
  int t = threadIdx.x;
  __syncthreads();
  if (t < 192) {
    int pair = t % 96, half = t / 96;
    int p_loc = pair / 3, q = pair - (pair / 3) * 3;
    const float* pw = ar.proj_w + (size_t)q * DD + half * 64;
    const float* tr = tile + p_loc * 132 + half * 64;
    float sv = 0.f;
#pragma unroll 8
    for (int d = 0; d < 64; ++d) sv += tr[d] * pw[d];
    red[t] = sv;
  }
  __syncthreads();
  if (t < 96) gq[t] = red[t] + red[96 + t];
  __syncthreads();
  if (t < PP) {
    const float* pw = ar.pred_w + (size_t)t * LL + l0;
    float s0 = 0.f, s1 = 0.f, s2 = 0.f;
#pragma unroll 8
    for (int l = 0; l < 32; ++l) {
      float w = pw[l];
      s0 += w * gq[l * 3 + 0];
      s1 += w * gq[l * 3 + 1];
      s2 += w * gq[l * 3 + 2];
    }
    float* op = ar.out + (size_t)n * (PP * QQ) + t * 3;
    atomicAdd(op + 0, s0);
    atomicAdd(op + 1, s1);
    atomicAdd(op + 2, s2);
  }
}

// cheby role: NS = K slices; slice 0 = T0 (A = ones), slices 1..NS-1 = planes.
// B-fragments pre-loaded per slice into register arrays (load/compute split).
template <int NS>
__device__ __forceinline__ void cheby_core(
    const MainArgs& ar, int band, int n, int l0, short* sU, float* blx,
    float* red, float* gq) {
  int t = threadIdx.x;
  const float* brow = ar.bands + ((size_t)band * NB + n) * LL;
  const float* ew = ar.emb_w;
  if (t < 34) blx[t] = brow[(l0 - 1 + t + LL) & 511];
  __syncthreads();
  for (int idx = t; idx < 32 * DD; idx += 256) {
    int l = idx >> 7, dch = idx & 127;
    float e = ew[dch * 3] * blx[l] + ew[dch * 3 + 1] * blx[l + 1] +
              ew[dch * 3 + 2] * blx[l + 2];
    float x = fast_tanh(e);
    int o = l * 136 + dch;
    sU[o] = f2bf(x);
    if (NS >= 3) {
      float t2 = 2.f * x * x - 1.f;
      sU[4352 + o] = f2bf(t2);
      if (NS >= 4) {
        float t3 = 2.f * x * t2 - x;
        sU[8704 + o] = f2bf(t3);
        if (NS >= 5) sU[13056 + o] = f2bf(2.f * x * t3 - t2);
      }
    }
  }
  __syncthreads();

  int w = t >> 6, lane = t & 63;
  int r16 = lane & 15, kq = lane >> 4;
  const int sbase = (NS - 2) * (NS + 1) / 2;  // band slice offsets {0,2,5,9}
  const short8v* cfrv = (const short8v*)ar.cfr;
  const short ONEB = (short)0x3F80;  // bf16 1.0
  short8v ones = {ONEB, ONEB, ONEB, ONEB, ONEB, ONEB, ONEB, ONEB};
  f32x4 cacc[2][2];
#pragma unroll
  for (int i = 0; i < 2; ++i)
#pragma unroll
    for (int j = 0; j < 2; ++j) cacc[i][j] = (f32x4){0.f, 0.f, 0.f, 0.f};
#pragma unroll
  for (int s = 0; s < NS; ++s) {
    short8v bfr0[4], bfr1[4];
#pragma unroll
    for (int ks = 0; ks < 4; ++ks) {
      bfr0[ks] = cfrv[(((sbase + s) * 4 + ks) * 8 + w * 2 + 0) * 64 + lane];
      bfr1[ks] = cfrv[(((sbase + s) * 4 + ks) * 8 + w * 2 + 1) * 64 + lane];
    }
#pragma unroll
    for (int ks = 0; ks < 4; ++ks) {
      short8v a0, a1;
      if (s == 0) {
        a0 = ones;
        a1 = ones;
      } else {
        a0 = *(const short8v*)&sU[(s - 1) * 4352 + r16 * 136 + ks * 32 + kq * 8];
        a1 = *(const short8v*)&sU[(s - 1) * 4352 + (16 + r16) * 136 + ks * 32 + kq * 8];
      }
      cacc[0][0] = MFMA16(a0, bfr0[ks], cacc[0][0]);
      cacc[0][1] = MFMA16(a0, bfr1[ks], cacc[0][1]);
      cacc[1][0] = MFMA16(a1, bfr0[ks], cacc[1][0]);
      cacc[1][1] = MFMA16(a1, bfr1[ks], cacc[1][1]);
    }
  }
  __syncthreads();  // all MFMAs done reading planes before tile overlay
  float* tile = (float*)sU;  // [32][132] f32
  int row0 = kq * 4;
#pragma unroll
  for (int nt = 0; nt < 2; ++nt) {
    int dout = w * 32 + nt * 16 + r16;
#pragma unroll
    for (int m = 0; m < 2; ++m)
#pragma unroll
      for (int r = 0; r < 4; ++r)
        tile[(m * 16 + row0 + r) * 132 + dout] = cacc[m][nt][r];
  }
  proj_epilogue(ar, n, l0, tile, red, gq);
}

// conv role: B-fragments pre-loaded per tap into register arrays.
template <int DIL>
__device__ __forceinline__ void conv_core(
    const MainArgs& ar, int band, int n, int l0, short* sU, float* blx2,
    float* red, float* gq) {
  int t = threadIdx.x;
  const float* brow = ar.bands + ((size_t)band * NB + n) * LL;
  const float* ew = ar.emb_w;
  if (t < 66) blx2[t] = brow[(l0 - 2 * DIL - 1 + t + LL) & 511];
  __syncthreads();

  // emb extended tile: rows v in [0, 32+4*DIL), l = l0-2*DIL+v, zero outside
  const int ETR = 32 + 4 * DIL;  // 36/40/48/64
  for (int idx = t; idx < ETR * DD; idx += 256) {
    int v = idx >> 7, dch = idx & 127;
    int l = l0 - 2 * DIL + v;
    float e = 0.f;
    if (l >= 0 && l < LL)
      e = ew[dch * 3] * blx2[v] + ew[dch * 3 + 1] * blx2[v + 1] +
          ew[dch * 3 + 2] * blx2[v + 2];
    sU[v * 136 + dch] = f2bf(e);
  }
  __syncthreads();

  int w = t >> 6, lane = t & 63;
  int r16 = lane & 15, kq = lane >> 4;
  const short8v* wfrv = (const short8v*)ar.wfr;

  // conv1 over 48 extended rows (3 M-tiles)
  const int m3a = (band * 2) * 3;
  f32x4 acc1[3][2];
#pragma unroll
  for (int i = 0; i < 3; ++i)
#pragma unroll
    for (int j = 0; j < 2; ++j) acc1[i][j] = (f32x4){0.f, 0.f, 0.f, 0.f};
#pragma unroll
  for (int tap = 0; tap < 3; ++tap) {
    short8v bfr0[4], bfr1[4];
#pragma unroll
    for (int ks = 0; ks < 4; ++ks) {
      bfr0[ks] = wfrv[(((m3a + tap) * 4 + ks) * 8 + w * 2 + 0) * 64 + lane];
      bfr1[ks] = wfrv[(((m3a + tap) * 4 + ks) * 8 + w * 2 + 1) * 64 + lane];
    }
#pragma unroll
    for (int ks = 0; ks < 4; ++ks) {
#pragma unroll
      for (int m = 0; m < 3; ++m) {
        short8v av = *(const short8v*)&sU[(m * 16 + r16 + tap * DIL) * 136 + ks * 32 + kq * 8];
        acc1[m][0] = MFMA16(av, bfr0[ks], acc1[m][0]);
        acc1[m][1] = MFMA16(av, bfr1[ks], acc1[m][1]);
      }
    }
  }
  // y1_ext rows u (y1 at l = l0-DIL+u), zero outside valid range
  {
    float bias0 = ar.b1[band][w * 32 + r16];
    float bias1 = ar.b1[band][w * 32 + 16 + r16];
#pragma unroll
    for (int m = 0; m < 3; ++m)
#pragma unroll
      for (int r = 0; r < 4; ++r) {
        int u = m * 16 + kq * 4 + r;
        int l = l0 - DIL + u;
        bool valid = (l >= 0) && (l < LL) && (u < 32 + 2 * DIL);
        short v0 = valid ? f2bf(fast_gelu(acc1[m][0][r] + bias0)) : (short)0;
        short v1 = valid ? f2bf(fast_gelu(acc1[m][1][r] + bias1)) : (short)0;
        sU[8704 + u * 136 + w * 32 + r16] = v0;
        sU[8704 + u * 136 + w * 32 + 16 + r16] = v1;
      }
  }
  __syncthreads();

  // conv2 (A = y1_ext rows u = p + tap*DIL)
  const int m3b = (band * 2 + 1) * 3;
  f32x4 acc2[2][2];
#pragma unroll
  for (int i = 0; i < 2; ++i)
#pragma unroll
    for (int j = 0; j < 2; ++j) acc2[i][j] = (f32x4){0.f, 0.f, 0.f, 0.f};
#pragma unroll
  for (int tap = 0; tap < 3; ++tap) {
    short8v bfr0[4], bfr1[4];
#pragma unroll
    for (int ks = 0; ks < 4; ++ks) {
      bfr0[ks] = wfrv[(((m3b + tap) * 4 + ks) * 8 + w * 2 + 0) * 64 + lane];
      bfr1[ks] = wfrv[(((m3b + tap) * 4 + ks) * 8 + w * 2 + 1) * 64 + lane];
    }
#pragma unroll
    for (int ks = 0; ks < 4; ++ks) {
#pragma unroll
      for (int m = 0; m < 2; ++m) {
        short8v av = *(const short8v*)&sU[8704 + (m * 16 + r16 + tap * DIL) * 136 + ks * 32 + kq * 8];
        acc2[m][0] = MFMA16(av, bfr0[ks], acc2[m][0]);
        acc2[m][1] = MFMA16(av, bfr1[ks], acc2[m][1]);
      }
    }
  }

  // tile = gelu(conv2 + b2) + emb residual (f32 overlay, disjoint from y1_ext)
  float* tile = (float*)sU;
#pragma unroll
  for (int nt = 0; nt < 2; ++nt) {
    int dout = w * 32 + nt * 16 + r16;
    float b2v = ar.b2[band][dout];
    float w0 = ew[dout * 3], w1 = ew[dout * 3 + 1], w2 = ew[dout * 3 + 2];
#pragma unroll
    for (int m = 0; m < 2; ++m)
#pragma unroll
      for (int r = 0; r < 4; ++r) {
        int p = m * 16 + kq * 4 + r;
        float eres = w0 * blx2[p + 2 * DIL] + w1 * blx2[p + 2 * DIL + 1] +
                     w2 * blx2[p + 2 * DIL + 2];
        tile[p * 132 + dout] = fast_gelu(acc2[m][nt][r] + b2v) + eres;
      }
  }
  proj_epilogue(ar, n, l0, tile, red, gq);
}

__global__ __launch_bounds__(256) void main_kernel(MainArgs ar) {
  __shared__ __align__(16) short sU[17408];
  __shared__ float blx[80];
  __shared__ float red[192];
  __shared__ float gq[96];
  int bid = blockIdx.x;
  int role = bid & 1, band = (bid >> 1) & 3, n = (bid >> 3) & 7;
  int l0 = (bid >> 6) << 5;
  if (role == 0) {
    switch (band) {
      case 0: cheby_core<2>(ar, band, n, l0, sU, blx, red, gq); break;
      case 1: cheby_core<3>(ar, band, n, l0, sU, blx, red, gq); break;
      case 2: cheby_core<4>(ar, band, n, l0, sU, blx, red, gq); break;
      default: cheby_core<5>(ar, band, n, l0, sU, blx, red, gq); break;
    }
  } else {
    switch (band) {
      case 0: conv_core<1>(ar, band, n, l0, sU, blx, red, gq); break;
      case 1: conv_core<2>(ar, band, n, l0, sU, blx, red, gq); break;
      case 2: conv_core<4>(ar, band, n, l0, sU, blx, red, gq); break;
      default: conv_core<8>(ar, band, n, l0, sU, blx, red, gq); break;
    }
  }
}

extern "C" void kernel_launch(void* const* d_in, const int* in_sizes, int n_in,
                              void* d_out, int out_size, void* d_ws, size_t ws_size,
                              hipStream_t stream) {
  const float* emb_w = (const float*)d_in[1];
  const float* proj_w = (const float*)d_in[22];
  const float* proj_b = (const float*)d_in[23];
  const float* pred_w = (const float*)d_in[24];
  const float* pred_b = (const float*)d_in[25];
  float* ws = (float*)d_ws;
  float* bands = ws + WS_BANDS;
  short* cfr = (short*)(ws + WS_CFR);
  short* wfr = (short*)(ws + WS_WFR);
  float* out = (float*)d_out;

  PrepArgs pa;
  pa.x_enc = (const float*)d_in[0];
  for (int i = 0; i < 4; ++i) {
    pa.cheb[i] = (const float*)d_in[2 + 5 * i];
    pa.w1[i] = (const float*)d_in[3 + 5 * i];
    pa.w2[i] = (const float*)d_in[5 + 5 * i];
  }
  pa.pred_b = pred_b; pa.proj_w = proj_w; pa.proj_b = proj_b;
  pa.bands = bands; pa.cfr = cfr; pa.wfr = wfr; pa.out = out;

  MainArgs ma;
  ma.emb_w = emb_w; ma.bands = bands; ma.cfr = cfr; ma.wfr = wfr;
  ma.proj_w = proj_w; ma.pred_w = pred_w;
  for (int i = 0; i < 4; ++i) {
    ma.b1[i] = (const float*)d_in[4 + 5 * i];
    ma.b2[i] = (const float*)d_in[6 + 5 * i];
  }
  ma.out = out;

  prep_kernel<<<161, 256, 0, stream>>>(pa);
  main_kernel<<<1024, 256, 0, stream>>>(ma);
}

// Round 20
// 33.045 us; speedup vs baseline: 1.1211x; 1.0048x over previous
//
#include <hip/hip_runtime.h>
#include <math.h>

#define NB 8      // only channel 0 of C=32 survives the final slice
#define LL 512
#define DD 128
#define PP 96
#define QQ 3

// workspace layout (float offsets)
#define WS_BANDS 0
#define WS_CFR   16384                 // 229376 shorts = 114688 f32 (14 slices)
#define WS_WFR   (WS_CFR + 114688)     // 393216 shorts = 196608 f32
#define WS_PWT   (WS_WFR + 196608)     // 49152 f32: pred_w^T [l][p]

typedef __attribute__((ext_vector_type(8))) short short8v;
typedef __attribute__((ext_vector_type(4))) float f32x4;

#define MFMA16(a, b, c) __builtin_amdgcn_mfma_f32_16x16x32_bf16(a, b, c, 0, 0, 0)

__device__ __forceinline__ short f2bf(float f) {
  unsigned u = __builtin_bit_cast(unsigned, f);
  unsigned r = (u + 0x7fffu + ((u >> 16) & 1u)) >> 16;
  return (short)r;
}

// fast tanh via hardware exp + rcp: tanh(x) = sign(x)*(1-e)*rcp(1+e), e=exp(-2|x|)
__device__ __forceinline__ float fast_tanh(float x) {
  float ax = fabsf(x);
  float e = __expf(-2.0f * ax);
  float r = (1.0f - e) * __builtin_amdgcn_rcpf(1.0f + e);
  return x < 0.0f ? -r : r;
}

// tanh-form GELU via sigmoid identity: 0.5*(1+tanh(u)) == 1/(1+exp(-2u)).
// Algebraically identical to 0.5*x*(1+tanh(u)); overflow-safe (rcp(inf)=0).
__device__ __forceinline__ float fast_gelu(float x) {
  float u = 0.7978845608028654f * x * (1.0f + 0.044715f * x * x);
  return x * __builtin_amdgcn_rcpf(1.0f + __expf(-2.0f * u));
}

constexpr float W_LO[8] = {
  -0.010597401784997278f, 0.032883011666982945f, 0.030841381835986965f,
  -0.18703481171888114f, -0.02798376941698385f, 0.6308807679295904f,
  0.7148465705525415f, 0.23037781330885523f
};

// ---------------- DWT helpers (validated round 0/1) ----------------
__device__ void dwt_level(const float* xin, int n, float* a, float* d,
                          int tid, int nthr) {
  int outn = (n + 5) / 2 + 1;
  for (int j = tid; j < outn; j += nthr) {
    float sa = 0.f, sd = 0.f;
#pragma unroll
    for (int k = 0; k < 8; ++k) {
      int i = 2 * j + k;
      int idx = (i < 6) ? (5 - i) : ((i < n + 6) ? (i - 6) : (2 * n + 5 - i));
      float v = xin[idx];
      sa += v * W_LO[7 - k];
      sd += v * ((k & 1) ? -W_LO[k] : W_LO[k]);
    }
    a[j] = sa;
    d[j] = sd;
  }
}

__device__ void idwt_level(const float* a, const float* d, float* out, int n,
                           int tid, int nthr) {
  int outn = 2 * n - 6;
  for (int t = tid; t < outn; t += nthr) {
    float s = 0.f;
#pragma unroll
    for (int k = 0; k < 8; ++k) {
      int j = t - 1 + k;
      if (j >= 0 && j <= 2 * n - 2 && ((j & 1) == 0)) {
        int m = j >> 1;
        if (a) s += a[m] * W_LO[k];
        if (d) s += d[m] * ((k & 1) ? W_LO[7 - k] : -W_LO[7 - k]);
      }
    }
    out[t] = s;
  }
}

// ---------------- K0: DWT (32) + packing (128) + out-bias init (1) ----------
struct PrepArgs {
  const float* x_enc;
  const float* cheb[4];
  const float* w1[4];
  const float* w2[4];
  const float* pred_b;
  const float* pred_w;
  const float* proj_w;
  const float* proj_b;
  float* bands;
  short* cfr;  // [slice14][ks4][nt8][lane64][e8]; band slice offsets {0,2,5,9}
  short* wfr;  // [(band*2+which)*3+tap][ks4][nt8][lane64][e8]
  float* pwt;  // [l][p] = pred_w[p][l]
  float* out;  // initialized to pred_b[p]*S[q] + proj_b[q]
};

__global__ __launch_bounds__(256) void prep_kernel(PrepArgs a) {
  __shared__ float sx[LL];
  __shared__ float a1[259], d1[259], a2[133], d2[133], a3[70], d3[70];
  __shared__ float rA[LL], rB[LL];
  int bid = blockIdx.x, t = threadIdx.x;
  if (bid < 32) {
    int n = bid & 7, band = bid >> 3;
    for (int l = t; l < LL; l += 256)
      sx[l] = a.x_enc[(size_t)n * LL * 32 + (size_t)l * 32];  // channel 0
    __syncthreads();
    dwt_level(sx, 512, a1, d1, t, 256); __syncthreads();
    dwt_level(a1, 259, a2, d2, t, 256); __syncthreads();
    dwt_level(a2, 133, a3, d3, t, 256); __syncthreads();
    idwt_level(band == 0 ? a3 : nullptr, band == 1 ? d3 : nullptr, rA, 70, t, 256);
    __syncthreads();
    idwt_level(rA, band == 2 ? d2 : nullptr, rB, 133, t, 256);
    __syncthreads();
    idwt_level(rB, band == 3 ? d1 : nullptr, rA, 259, t, 256);
    __syncthreads();
    float* dstb = a.bands + ((size_t)band * NB + n) * LL;
    for (int l = t; l < LL; l += 256) dstb[l] = rA[l];
  } else if (bid < 160) {
    // packing: 14 cheby slices (incl. k=0) + 24 conv slices + pred_w^T
    const int CFRG = 28672, WFRG = 49152, PWTN = LL * PP;
    const int total = CFRG + WFRG + PWTN;
    for (int g = (bid - 32) * 256 + t; g < total; g += 128 * 256) {
      if (g < CFRG) {
        int gs = g >> 11, r = g & 2047;  // 2048 groups/slice
        int ks = r >> 9, r2 = r & 511;
        int nt = r2 >> 6, lane = r2 & 63;
        int b = (gs >= 9) ? 3 : ((gs >= 5) ? 2 : ((gs >= 2) ? 1 : 0));
        int off = (b == 3) ? 9 : ((b == 2) ? 5 : ((b == 1) ? 2 : 0));
        int kcoef = gs - off;  // 0..K-1 (0 = T0 slice)
        int K = b + 2;
        int din0 = ks * 32 + (lane >> 4) * 8;
        int dout = nt * 16 + (lane & 15);
        const float* src = a.cheb[b];
        short8v v;
#pragma unroll
        for (int el = 0; el < 8; ++el)
          v[el] = f2bf(src[((size_t)(din0 + el) * DD + dout) * K + kcoef]);
        ((short8v*)a.cfr)[g] = v;
      } else if (g < CFRG + WFRG) {
        int g2 = g - CFRG;
        int m = g2 >> 11, r = g2 & 2047;
        int ks = r >> 9, r2 = r & 511;
        int nt = r2 >> 6, lane = r2 & 63;
        int bw = m / 3, tap = m - bw * 3;
        int band = bw >> 1, which = bw & 1;
        const float* w = which ? a.w2[band] : a.w1[band];
        int din0 = ks * 32 + (lane >> 4) * 8;
        int dout = nt * 16 + (lane & 15);
        short8v v;
#pragma unroll
        for (int el = 0; el < 8; ++el)
          v[el] = f2bf(w[((size_t)dout * DD + din0 + el) * 3 + tap]);
        ((short8v*)a.wfr)[g2] = v;
      } else {
        int e = g - CFRG - WFRG;  // e = l*96 + p (coalesced write)
        int l = e / PP, p = e - l * PP;
        a.pwt[e] = a.pred_w[(size_t)p * LL + l];
      }
    }
  } else {
    // out[n][p][q] = pred_b[p]*S[q] + proj_b[q], S[q] = sum_d proj_w[q][d]
    __shared__ float S[4];
    if (t < QQ) {
      const float4* pw = (const float4*)(a.proj_w + (size_t)t * DD);
      float s = 0.f;
#pragma unroll
      for (int i = 0; i < 32; ++i) {
        float4 v = pw[i];
        s += v.x + v.y + v.z + v.w;
      }
      S[t] = s;
    }
    __syncthreads();
    for (int i = t; i < NB * PP * QQ; i += 256) {
      int pq = i % (PP * QQ);
      int p = pq / QQ, q = pq - p * QQ;
      a.out[i] = a.pred_b[p] * S[q] + a.proj_b[q];
    }
  }
}

// ---------------- main: role-split, 32-pos tiles, full-output epilogue -------
struct MainArgs {
  const float* emb_w;
  const float* bands;
  const short* cfr;
  const short* wfr;
  const float* proj_w;
  const float* pwt;
  const float* b1[4];
  const float* b2[4];
  float* out;
};

// epilogue: tile[32][132] f32 in LDS -> proj dot (192 lanes, split-d) ->
// gq[32][3] -> pred contraction (coalesced pwt reads) -> atomicAdd into out.
__device__ __forceinline__ void proj_epilogue(
    const MainArgs& ar, int n, int l0, float* tile, float* red, float* gq) {
  int t = threadIdx.x;
  __syncthreads();
  if (t < 192) {
    int pair = t % 96, half = t / 96;
    int p_loc = pair / 3, q = pair - (pair / 3) * 3;
    const float* pw = ar.proj_w + (size_t)q * DD + half * 64;
    const float* tr = tile + p_loc * 132 + half * 64;
    float sv = 0.f;
#pragma unroll 8
    for (int d = 0; d < 64; ++d) sv += tr[d] * pw[d];
    red[t] = sv;
  }
  __syncthreads();
  if (t < 96) gq[t] = red[t] + red[96 + t];
  __syncthreads();
  if (t < PP) {
    const float* pw = ar.pwt + (size_t)l0 * PP + t;  // [l][p], coalesced in t
    float s0 = 0.f, s1 = 0.f, s2 = 0.f;
#pragma unroll 8
    for (int l = 0; l < 32; ++l) {
      float w = pw[l * PP];
      s0 += w * gq[l * 3 + 0];
      s1 += w * gq[l * 3 + 1];
      s2 += w * gq[l * 3 + 2];
    }
    float* op = ar.out + (size_t)n * (PP * QQ) + t * 3;
    atomicAdd(op + 0, s0);
    atomicAdd(op + 1, s1);
    atomicAdd(op + 2, s2);
  }
}

// cheby role: NS = K slices; slice 0 = T0 (A = ones), slices 1..NS-1 = planes.
// B-fragments pre-loaded per slice into register arrays (load/compute split).
template <int NS>
__device__ __forceinline__ void cheby_core(
    const MainArgs& ar, int band, int n, int l0, short* sU, float* blx,
    float* red, float* gq) {
  int t = threadIdx.x;
  const float* brow = ar.bands + ((size_t)band * NB + n) * LL;
  const float* ew = ar.emb_w;
  if (t < 34) blx[t] = brow[(l0 - 1 + t + LL) & 511];
  __syncthreads();
  for (int idx = t; idx < 32 * DD; idx += 256) {
    int l = idx >> 7, dch = idx & 127;
    float e = ew[dch * 3] * blx[l] + ew[dch * 3 + 1] * blx[l + 1] +
              ew[dch * 3 + 2] * blx[l + 2];
    float x = fast_tanh(e);
    int o = l * 136 + dch;
    sU[o] = f2bf(x);
    if (NS >= 3) {
      float t2 = 2.f * x * x - 1.f;
      sU[4352 + o] = f2bf(t2);
      if (NS >= 4) {
        float t3 = 2.f * x * t2 - x;
        sU[8704 + o] = f2bf(t3);
        if (NS >= 5) sU[13056 + o] = f2bf(2.f * x * t3 - t2);
      }
    }
  }
  __syncthreads();

  int w = t >> 6, lane = t & 63;
  int r16 = lane & 15, kq = lane >> 4;
  const int sbase = (NS - 2) * (NS + 1) / 2;  // band slice offsets {0,2,5,9}
  const short8v* cfrv = (const short8v*)ar.cfr;
  const short ONEB = (short)0x3F80;  // bf16 1.0
  short8v ones = {ONEB, ONEB, ONEB, ONEB, ONEB, ONEB, ONEB, ONEB};
  f32x4 cacc[2][2];
#pragma unroll
  for (int i = 0; i < 2; ++i)
#pragma unroll
    for (int j = 0; j < 2; ++j) cacc[i][j] = (f32x4){0.f, 0.f, 0.f, 0.f};
#pragma unroll
  for (int s = 0; s < NS; ++s) {
    short8v bfr0[4], bfr1[4];
#pragma unroll
    for (int ks = 0; ks < 4; ++ks) {
      bfr0[ks] = cfrv[(((sbase + s) * 4 + ks) * 8 + w * 2 + 0) * 64 + lane];
      bfr1[ks] = cfrv[(((sbase + s) * 4 + ks) * 8 + w * 2 + 1) * 64 + lane];
    }
#pragma unroll
    for (int ks = 0; ks < 4; ++ks) {
      short8v a0, a1;
      if (s == 0) {
        a0 = ones;
        a1 = ones;
      } else {
        a0 = *(const short8v*)&sU[(s - 1) * 4352 + r16 * 136 + ks * 32 + kq * 8];
        a1 = *(const short8v*)&sU[(s - 1) * 4352 + (16 + r16) * 136 + ks * 32 + kq * 8];
      }
      cacc[0][0] = MFMA16(a0, bfr0[ks], cacc[0][0]);
      cacc[0][1] = MFMA16(a0, bfr1[ks], cacc[0][1]);
      cacc[1][0] = MFMA16(a1, bfr0[ks], cacc[1][0]);
      cacc[1][1] = MFMA16(a1, bfr1[ks], cacc[1][1]);
    }
  }
  __syncthreads();  // all MFMAs done reading planes before tile overlay
  float* tile = (float*)sU;  // [32][132] f32
  int row0 = kq * 4;
#pragma unroll
  for (int nt = 0; nt < 2; ++nt) {
    int dout = w * 32 + nt * 16 + r16;
#pragma unroll
    for (int m = 0; m < 2; ++m)
#pragma unroll
      for (int r = 0; r < 4; ++r)
        tile[(m * 16 + row0 + r) * 132 + dout] = cacc[m][nt][r];
  }
  proj_epilogue(ar, n, l0, tile, red, gq);
}

// conv role: B-fragments pre-loaded per tap into register arrays.
template <int DIL>
__device__ __forceinline__ void conv_core(
    const MainArgs& ar, int band, int n, int l0, short* sU, float* blx2,
    float* red, float* gq) {
  int t = threadIdx.x;
  const float* brow = ar.bands + ((size_t)band * NB + n) * LL;
  const float* ew = ar.emb_w;
  if (t < 66) blx2[t] = brow[(l0 - 2 * DIL - 1 + t + LL) & 511];
  __syncthreads();

  // emb extended tile: rows v in [0, 32+4*DIL), l = l0-2*DIL+v, zero outside
  const int ETR = 32 + 4 * DIL;  // 36/40/48/64
  for (int idx = t; idx < ETR * DD; idx += 256) {
    int v = idx >> 7, dch = idx & 127;
    int l = l0 - 2 * DIL + v;
    float e = 0.f;
    if (l >= 0 && l < LL)
      e = ew[dch * 3] * blx2[v] + ew[dch * 3 + 1] * blx2[v + 1] +
          ew[dch * 3 + 2] * blx2[v + 2];
    sU[v * 136 + dch] = f2bf(e);
  }
  __syncthreads();

  int w = t >> 6, lane = t & 63;
  int r16 = lane & 15, kq = lane >> 4;
  const short8v* wfrv = (const short8v*)ar.wfr;

  // conv1 over 48 extended rows (3 M-tiles)
  const int m3a = (band * 2) * 3;
  f32x4 acc1[3][2];
#pragma unroll
  for (int i = 0; i < 3; ++i)
#pragma unroll
    for (int j = 0; j < 2; ++j) acc1[i][j] = (f32x4){0.f, 0.f, 0.f, 0.f};
#pragma unroll
  for (int tap = 0; tap < 3; ++tap) {
    short8v bfr0[4], bfr1[4];
#pragma unroll
    for (int ks = 0; ks < 4; ++ks) {
      bfr0[ks] = wfrv[(((m3a + tap) * 4 + ks) * 8 + w * 2 + 0) * 64 + lane];
      bfr1[ks] = wfrv[(((m3a + tap) * 4 + ks) * 8 + w * 2 + 1) * 64 + lane];
    }
#pragma unroll
    for (int ks = 0; ks < 4; ++ks) {
#pragma unroll
      for (int m = 0; m < 3; ++m) {
        short8v av = *(const short8v*)&sU[(m * 16 + r16 + tap * DIL) * 136 + ks * 32 + kq * 8];
        acc1[m][0] = MFMA16(av, bfr0[ks], acc1[m][0]);
        acc1[m][1] = MFMA16(av, bfr1[ks], acc1[m][1]);
      }
    }
  }
  // y1_ext rows u (y1 at l = l0-DIL+u), zero outside valid range
  {
    float bias0 = ar.b1[band][w * 32 + r16];
    float bias1 = ar.b1[band][w * 32 + 16 + r16];
#pragma unroll
    for (int m = 0; m < 3; ++m)
#pragma unroll
      for (int r = 0; r < 4; ++r) {
        int u = m * 16 + kq * 4 + r;
        int l = l0 - DIL + u;
        bool valid = (l >= 0) && (l < LL) && (u < 32 + 2 * DIL);
        short v0 = valid ? f2bf(fast_gelu(acc1[m][0][r] + bias0)) : (short)0;
        short v1 = valid ? f2bf(fast_gelu(acc1[m][1][r] + bias1)) : (short)0;
        sU[8704 + u * 136 + w * 32 + r16] = v0;
        sU[8704 + u * 136 + w * 32 + 16 + r16] = v1;
      }
  }
  __syncthreads();

  // conv2 (A = y1_ext rows u = p + tap*DIL)
  const int m3b = (band * 2 + 1) * 3;
  f32x4 acc2[2][2];
#pragma unroll
  for (int i = 0; i < 2; ++i)
#pragma unroll
    for (int j = 0; j < 2; ++j) acc2[i][j] = (f32x4){0.f, 0.f, 0.f, 0.f};
#pragma unroll
  for (int tap = 0; tap < 3; ++tap) {
    short8v bfr0[4], bfr1[4];
#pragma unroll
    for (int ks = 0; ks < 4; ++ks) {
      bfr0[ks] = wfrv[(((m3b + tap) * 4 + ks) * 8 + w * 2 + 0) * 64 + lane];
      bfr1[ks] = wfrv[(((m3b + tap) * 4 + ks) * 8 + w * 2 + 1) * 64 + lane];
    }
#pragma unroll
    for (int ks = 0; ks < 4; ++ks) {
#pragma unroll
      for (int m = 0; m < 2; ++m) {
        short8v av = *(const short8v*)&sU[8704 + (m * 16 + r16 + tap * DIL) * 136 + ks * 32 + kq * 8];
        acc2[m][0] = MFMA16(av, bfr0[ks], acc2[m][0]);
        acc2[m][1] = MFMA16(av, bfr1[ks], acc2[m][1]);
      }
    }
  }

  // tile = gelu(conv2 + b2) + emb residual (f32 overlay, disjoint from y1_ext)
  float* tile = (float*)sU;
#pragma unroll
  for (int nt = 0; nt < 2; ++nt) {
    int dout = w * 32 + nt * 16 + r16;
    float b2v = ar.b2[band][dout];
    float w0 = ew[dout * 3], w1 = ew[dout * 3 + 1], w2 = ew[dout * 3 + 2];
#pragma unroll
    for (int m = 0; m < 2; ++m)
#pragma unroll
      for (int r = 0; r < 4; ++r) {
        int p = m * 16 + kq * 4 + r;
        float eres = w0 * blx2[p + 2 * DIL] + w1 * blx2[p + 2 * DIL + 1] +
                     w2 * blx2[p + 2 * DIL + 2];
        tile[p * 132 + dout] = fast_gelu(acc2[m][nt][r] + b2v) + eres;
      }
  }
  proj_epilogue(ar, n, l0, tile, red, gq);
}

__global__ __launch_bounds__(256) void main_kernel(MainArgs ar) {
  __shared__ __align__(16) short sU[17408];
  __shared__ float blx[80];
  __shared__ float red[192];
  __shared__ float gq[96];
  int bid = blockIdx.x;
  int role = bid & 1, band = (bid >> 1) & 3, n = (bid >> 3) & 7;
  int l0 = (bid >> 6) << 5;
  if (role == 0) {
    switch (band) {
      case 0: cheby_core<2>(ar, band, n, l0, sU, blx, red, gq); break;
      case 1: cheby_core<3>(ar, band, n, l0, sU, blx, red, gq); break;
      case 2: cheby_core<4>(ar, band, n, l0, sU, blx, red, gq); break;
      default: cheby_core<5>(ar, band, n, l0, sU, blx, red, gq); break;
    }
  } else {
    switch (band) {
      case 0: conv_core<1>(ar, band, n, l0, sU, blx, red, gq); break;
      case 1: conv_core<2>(ar, band, n, l0, sU, blx, red, gq); break;
      case 2: conv_core<4>(ar, band, n, l0, sU, blx, red, gq); break;
      default: conv_core<8>(ar, band, n, l0, sU, blx, red, gq); break;
    }
  }
}

extern "C" void kernel_launch(void* const* d_in, const int* in_sizes, int n_in,
                              void* d_out, int out_size, void* d_ws, size_t ws_size,
                              hipStream_t stream) {
  const float* emb_w = (const float*)d_in[1];
  const float* proj_w = (const float*)d_in[22];
  const float* proj_b = (const float*)d_in[23];
  const float* pred_w = (const float*)d_in[24];
  const float* pred_b = (const float*)d_in[25];
  float* ws = (float*)d_ws;
  float* bands = ws + WS_BANDS;
  short* cfr = (short*)(ws + WS_CFR);
  short* wfr = (short*)(ws + WS_WFR);
  float* pwt = ws + WS_PWT;
  float* out = (float*)d_out;

  PrepArgs pa;
  pa.x_enc = (const float*)d_in[0];
  for (int i = 0; i < 4; ++i) {
    pa.cheb[i] = (const float*)d_in[2 + 5 * i];
    pa.w1[i] = (const float*)d_in[3 + 5 * i];
    pa.w2[i] = (const float*)d_in[5 + 5 * i];
  }
  pa.pred_b = pred_b; pa.pred_w = pred_w; pa.proj_w = proj_w; pa.proj_b = proj_b;
  pa.bands = bands; pa.cfr = cfr; pa.wfr = wfr; pa.pwt = pwt; pa.out = out;

  MainArgs ma;
  ma.emb_w = emb_w; ma.bands = bands; ma.cfr = cfr; ma.wfr = wfr;
  ma.proj_w = proj_w; ma.pwt = pwt;
  for (int i = 0; i < 4; ++i) {
    ma.b1[i] = (const float*)d_in[4 + 5 * i];
    ma.b2[i] = (const float*)d_in[6 + 5 * i];
  }
  ma.out = out;

  prep_kernel<<<161, 256, 0, stream>>>(pa);
  main_kernel<<<1024, 256, 0, stream>>>(ma);
}